// Round 8
// baseline (1834.199 us; speedup 1.0000x reference)
//
#include <hip/hip_runtime.h>

typedef __attribute__((ext_vector_type(8))) short bf16x8;
typedef __attribute__((ext_vector_type(4))) float f32x4;

#define N_NODES   100000
#define NPERM_    100000
#define L_        16
#define G_        1024
#define CAP_      20
#define OVF_MAX   4096

__device__ inline unsigned short f32_to_bf16(float f) {
    unsigned u = __float_as_uint(f);
    unsigned r = (u + 0x7fff + ((u >> 16) & 1)) >> 16;   // RNE
    return (unsigned short)r;
}
__device__ inline float bflo(unsigned u) { return __uint_as_float(u << 16); }
__device__ inline float bfhi(unsigned u) { return __uint_as_float(u & 0xffff0000u); }
__device__ inline unsigned pk2(float a, float b) {
    return (unsigned)f32_to_bf16(a) | ((unsigned)f32_to_bf16(b) << 16);
}

// ---------------------------------------------------------------------------
// W_lrp [4][64 k][64 c][16 l] -> split bf16 (hi + residual), [4][16 l][64 c][64 k]
__global__ __launch_bounds__(256) void k_prep_w(const float* __restrict__ W,
                                                unsigned short* __restrict__ Wh,
                                                unsigned short* __restrict__ Wl) {
    int o = blockIdx.x * 256 + threadIdx.x;   // 262144
    int k = o & 63, c = (o >> 6) & 63, l = (o >> 12) & 15, i = o >> 16;
    float f = W[(((i * 64 + k) * 64) + c) * 16 + l];
    unsigned short hh = f32_to_bf16(f);
    float fl = f - __uint_as_float(((unsigned)hh) << 16);
    Wh[o] = hh;
    Wl[o] = f32_to_bf16(fl);
}

// ---------------------------------------------------------------------------
// factor[n,c] = relu(degs[n]*A + B) @ W1 + b1 is piecewise-linear in degs[n].
// Per layer: sorted breakpoints thr[128], then for EACH segment evaluate the
// active set DIRECTLY at a representative g (robust to B==0, ties, no-cross).
__global__ __launch_bounds__(128) void k_prep_factor(const float* __restrict__ dn0_W,
                                                     const float* __restrict__ dn0_b,
                                                     const float* __restrict__ dn1_W,
                                                     const float* __restrict__ dn1_b,
                                                     float* __restrict__ tab,   // [4][129][64][2]
                                                     float* __restrict__ thr) { // [4][128]
    int i = blockIdx.x;            // layer
    int t = threadIdx.x;           // 128 threads
    __shared__ float A[128], B[128], ts[128], tv[128];
    A[t] = dn0_W[i * 128 + t];
    B[t] = dn0_b[i * 128 + t];
    __syncthreads();
    float a = A[t], b = B[t];
    float tj = -b / a;
    if (a == 0.f || !(tj > 0.f)) tj = 1e30f;   // no crossing in (0, inf)
    tv[t] = tj;
    __syncthreads();
    int rank = 0;
    for (int j = 0; j < 128; ++j) {
        float o = tv[j];
        rank += (o < tj) || (o == tj && j < t);
    }
    ts[rank] = tj;
    __syncthreads();
    thr[i * 128 + t] = ts[t];
    if (t < 64) {
        int c = t;
        const float* W1c = dn1_W + (size_t)i * 128 * 64 + c;   // stride 64
        float b1c = dn1_b[i * 64 + c];
        float* tb = tab + (size_t)i * 129 * 128;
        for (int s = 0; s <= 128; ++s) {
            float lo = (s == 0) ? 0.f : ts[s - 1];
            float hi = (s == 128) ? 1e30f : ts[s];
            float g;
            if (lo > 1e29f)       g = 1e29f;        // unreachable segment
            else if (hi > 1e29f)  g = lo + 1.f;     // unbounded: any g > lo
            else                  g = 0.5f * (lo + hi);
            float alpha = 0.f, beta = b1c;
            for (int j = 0; j < 128; ++j) {
                if (fmaf(g, A[j], B[j]) > 0.f) {
                    float w1 = W1c[j * 64];
                    alpha = fmaf(A[j], w1, alpha);
                    beta  = fmaf(B[j], w1, beta);
                }
            }
            tb[s * 128 + c * 2 + 0] = alpha;
            tb[s * 128 + c * 2 + 1] = beta;
        }
    }
}

// ---------------------------------------------------------------------------
// xb = bf16(node_feat @ atom_W + atom_b)
__global__ __launch_bounds__(256) void k_atom(const float* __restrict__ feat,
                                              const float* __restrict__ W,
                                              const float* __restrict__ b,
                                              unsigned short* __restrict__ xb) {
    __shared__ float Wlds[28 * 64];
    __shared__ float blds[64];
    int tid = threadIdx.x;
    for (int t = tid; t < 28 * 64; t += 256) Wlds[t] = W[t];
    if (tid < 64) blds[tid] = b[tid];
    __syncthreads();
    int n = blockIdx.x * 4 + (tid >> 6);
    int c = tid & 63;
    if (n >= N_NODES) return;
    const float* fr = feat + n * 28;
    float acc = blds[c];
#pragma unroll
    for (int j = 0; j < 28; ++j) acc = fmaf(fr[j], Wlds[j * 64 + c], acc);
    xb[n * 64 + c] = f32_to_bf16(acc);
}

// ---------------------------------------------------------------------------
__global__ __launch_bounds__(256) void k_bucket(const int* __restrict__ prow,
                                                int* __restrict__ cntn,
                                                int* __restrict__ bucket,
                                                int* __restrict__ ovf,
                                                int* __restrict__ ovfc) {
    int d = blockIdx.x * 256 + threadIdx.x;
    if (d >= NPERM_) return;
    int n = prow[d];
    int s = atomicAdd(cntn + n, 1);
    if (s < CAP_) bucket[n * CAP_ + s] = d;
    else { int o = atomicAdd(ovfc, 1); if (o < OVF_MAX) ovf[o] = d; }
}

// ---------------------------------------------------------------------------
// MFMA gather-GEMM:  h = relu( T(gather,bf16) @ (Whi+Wlo) + b )
// 2-phase-deep x-row pipeline (xvA/xvB ping-pong), LDS-bounce clean C-write.
__global__ __launch_bounds__(256, 4) void k_lrp(const unsigned short* __restrict__ xbuf,
                                                const int*   __restrict__ n2p_col,
                                                const float* __restrict__ n2p_val,
                                                const float* __restrict__ e2p_val,
                                                const float* __restrict__ edge_W,
                                                const float* __restrict__ edge_b,
                                                const unsigned short* __restrict__ Wth, // [16][64][64]
                                                const unsigned short* __restrict__ Wtl,
                                                const float* __restrict__ bl,
                                                float* __restrict__ hout) {
    __shared__ unsigned short Tb[128][72];
    __shared__ unsigned short Wh[64][72];
    __shared__ unsigned short Wo[64][72];
    __shared__ float efs[64];
    int tid = threadIdx.x;
    int lane = tid & 63;
    int w = tid >> 6;
    int d0 = blockIdx.x * 128;
    int dl = tid >> 1;
    int kq = tid & 1;
    int wc = tid >> 2;
    int wk = (tid & 3) * 16;
    int dg = d0 + dl;
    int dsafe = (dg < NPERM_) ? dg : 0;
    size_t pbase = (size_t)dsafe * 16;

    if (tid < 64) efs[tid] = edge_W[tid] + edge_b[tid];

    f32x4 acc[2][4];
#pragma unroll
    for (int aa = 0; aa < 2; ++aa)
#pragma unroll
        for (int cb = 0; cb < 4; ++cb) acc[aa][cb] = (f32x4)0.f;

    uint4 xvA[4], xvB[4], wvh0, wvh1, wvl0, wvl1;
    int   colN  = n2p_col[pbase + 2];
    int   colN2 = n2p_col[pbase + 3];
    float vnN   = n2p_val[pbase + 0];
    float veN   = e2p_val[pbase + 0];
    {
        int c0 = n2p_col[pbase + 0];
        int c1 = n2p_col[pbase + 1];
        const uint4* xr0 = (const uint4*)(xbuf + (size_t)c0 * 64 + kq * 32);
#pragma unroll
        for (int j = 0; j < 4; ++j) xvA[j] = xr0[j];
        const uint4* xr1 = (const uint4*)(xbuf + (size_t)c1 * 64 + kq * 32);
#pragma unroll
        for (int j = 0; j < 4; ++j) xvB[j] = xr1[j];
        const uint4* whr = (const uint4*)(Wth + wc * 64 + wk);
        wvh0 = whr[0]; wvh1 = whr[1];
        const uint4* wlr = (const uint4*)(Wtl + wc * 64 + wk);
        wvl0 = wlr[0]; wvl1 = wlr[1];
    }
    __syncthreads();   // efs visible

#define LRP_PHASE(LVAL, XV)                                                      \
    {                                                                            \
        const int l = (LVAL);                                                    \
        float vn = vnN, ve = veN;                                                \
        __syncthreads();                                                         \
        _Pragma("unroll")                                                        \
        for (int j = 0; j < 4; ++j) {                                            \
            uint4 v = XV[j];                                                     \
            int kb = kq * 32 + j * 8;                                            \
            float4 ea = *(const float4*)&efs[kb];                                \
            float4 eb = *(const float4*)&efs[kb + 4];                            \
            float t0 = fmaf(vn, bflo(v.x), ve * ea.x);                           \
            float t1 = fmaf(vn, bfhi(v.x), ve * ea.y);                           \
            float t2 = fmaf(vn, bflo(v.y), ve * ea.z);                           \
            float t3 = fmaf(vn, bfhi(v.y), ve * ea.w);                           \
            float t4 = fmaf(vn, bflo(v.z), ve * eb.x);                           \
            float t5 = fmaf(vn, bfhi(v.z), ve * eb.y);                           \
            float t6 = fmaf(vn, bflo(v.w), ve * eb.z);                           \
            float t7 = fmaf(vn, bfhi(v.w), ve * eb.w);                           \
            uint4 ow;                                                            \
            ow.x = pk2(t0, t1); ow.y = pk2(t2, t3);                              \
            ow.z = pk2(t4, t5); ow.w = pk2(t6, t7);                              \
            *(uint4*)&Tb[dl][kb] = ow;                                           \
        }                                                                        \
        *(uint4*)&Wh[wc][wk]     = wvh0;                                         \
        *(uint4*)&Wh[wc][wk + 8] = wvh1;                                         \
        *(uint4*)&Wo[wc][wk]     = wvl0;                                         \
        *(uint4*)&Wo[wc][wk + 8] = wvl1;                                         \
        __syncthreads();                                                         \
        if (l < 15) {                                                            \
            const uint4* whr = (const uint4*)(Wth + (l + 1) * 4096 + wc * 64 + wk); \
            wvh0 = whr[0]; wvh1 = whr[1];                                        \
            const uint4* wlr = (const uint4*)(Wtl + (l + 1) * 4096 + wc * 64 + wk); \
            wvl0 = wlr[0]; wvl1 = wlr[1];                                        \
            vnN = n2p_val[pbase + l + 1];                                        \
            veN = e2p_val[pbase + l + 1];                                        \
        }                                                                        \
        if (l < 14) {   /* issue row for l+2 into just-consumed buffer */        \
            const uint4* xr = (const uint4*)(xbuf + (size_t)colN * 64 + kq * 32);\
            _Pragma("unroll")                                                    \
            for (int j = 0; j < 4; ++j) XV[j] = xr[j];                           \
            colN = colN2;                                                        \
            if (l < 12) colN2 = n2p_col[pbase + l + 4];                          \
        }                                                                        \
        {                                                                        \
            int r = lane & 15, q = lane >> 4;                                    \
            _Pragma("unroll")                                                    \
            for (int s = 0; s < 2; ++s) {                                        \
                int ko = s * 32 + q * 8;                                         \
                bf16x8 a0 = *(const bf16x8*)&Tb[w * 32 + r][ko];                 \
                bf16x8 a1 = *(const bf16x8*)&Tb[w * 32 + 16 + r][ko];            \
                _Pragma("unroll")                                                \
                for (int cb = 0; cb < 4; ++cb) {                                 \
                    bf16x8 bh = *(const bf16x8*)&Wh[cb * 16 + r][ko];            \
                    bf16x8 bo = *(const bf16x8*)&Wo[cb * 16 + r][ko];            \
                    acc[0][cb] = __builtin_amdgcn_mfma_f32_16x16x32_bf16(a0, bh, acc[0][cb], 0, 0, 0); \
                    acc[0][cb] = __builtin_amdgcn_mfma_f32_16x16x32_bf16(a0, bo, acc[0][cb], 0, 0, 0); \
                    acc[1][cb] = __builtin_amdgcn_mfma_f32_16x16x32_bf16(a1, bh, acc[1][cb], 0, 0, 0); \
                    acc[1][cb] = __builtin_amdgcn_mfma_f32_16x16x32_bf16(a1, bo, acc[1][cb], 0, 0, 0); \
                }                                                                \
            }                                                                    \
        }                                                                        \
    }

#pragma unroll 1
    for (int lp = 0; lp < 8; ++lp) {
        LRP_PHASE(2 * lp,     xvA)
        LRP_PHASE(2 * lp + 1, xvB)
    }
#undef LRP_PHASE

    // epilogue: bias+relu, bounce through per-wave LDS slice, clean float4 rows
    __syncthreads();   // all MFMA reads of Tb done
    {
        int r = lane & 15, q = lane >> 4;
        float* F = (float*)(&Tb[0][0]) + w * 1024;   // 4 KB per wave
#pragma unroll
        for (int aa = 0; aa < 2; ++aa) {
#pragma unroll
            for (int cb = 0; cb < 4; ++cb) {
                float bias = bl[cb * 16 + r];
#pragma unroll
                for (int reg = 0; reg < 4; ++reg)
                    F[(q * 4 + reg) * 64 + cb * 16 + r] = fmaxf(acc[aa][cb][reg] + bias, 0.f);
            }
#pragma unroll
            for (int ii = 0; ii < 4; ++ii) {
                int idx = lane + ii * 64;            // 0..255 -> 16 rows x 16 float4
                float4 v = ((const float4*)F)[idx];
                int R = d0 + w * 32 + aa * 16 + (idx >> 4);
                if (R < NPERM_)
                    *(float4*)(hout + (size_t)R * 64 + (idx & 15) * 4) = v;
            }
        }
    }
}

// ---------------------------------------------------------------------------
// x[n] = (bucket-gather pool of h) * (alpha[seg]*degs + beta[seg])
// last=0: write bf16 shadow only;  last=1: write f32 x only.
__global__ __launch_bounds__(256) void k_pool_seg(const float* __restrict__ h,
                                                  const int*   __restrict__ cntn,
                                                  const int*   __restrict__ bucket,
                                                  const int*   __restrict__ ovf,
                                                  const int*   __restrict__ ovfc,
                                                  const int*   __restrict__ prow,
                                                  const float* __restrict__ pval,
                                                  const float* __restrict__ degs,
                                                  const float* __restrict__ tab,  // [129][64][2]
                                                  const float* __restrict__ thr,  // [128]
                                                  float* __restrict__ x,
                                                  unsigned short* __restrict__ xbo,
                                                  int last) {
    __shared__ float thrl[128];
    int tid = threadIdx.x;
    if (tid < 128) thrl[tid] = thr[tid];
    __syncthreads();
    int n  = blockIdx.x * 16 + (tid >> 4);
    int c4 = (tid & 15) * 4;
    if (n >= N_NODES) return;
    float dgv = degs[n];
    int seg = 0;
    if (thrl[63]       < dgv) seg = 64;
    if (thrl[seg + 31] < dgv) seg += 32;
    if (thrl[seg + 15] < dgv) seg += 16;
    if (thrl[seg + 7]  < dgv) seg += 8;
    if (thrl[seg + 3]  < dgv) seg += 4;
    if (thrl[seg + 1]  < dgv) seg += 2;
    if (thrl[seg]      < dgv) seg += 1;
    float4 p = make_float4(0.f, 0.f, 0.f, 0.f);
    int cn = min(cntn[n], CAP_);
    for (int j = 0; j < cn; ++j) {
        int   d  = bucket[n * CAP_ + j];
        float pv = pval[d];
        float4 hv = *(const float4*)(h + (size_t)d * 64 + c4);
        p.x = fmaf(pv, hv.x, p.x);
        p.y = fmaf(pv, hv.y, p.y);
        p.z = fmaf(pv, hv.z, p.z);
        p.w = fmaf(pv, hv.w, p.w);
    }
    int novf = *ovfc;
    if (novf > 0) {
        int ne = novf < OVF_MAX ? novf : OVF_MAX;
        for (int e = 0; e < ne; ++e) {
            int d = ovf[e];
            if (prow[d] == n) {
                float pv = pval[d];
                float4 hv = *(const float4*)(h + (size_t)d * 64 + c4);
                p.x = fmaf(pv, hv.x, p.x);
                p.y = fmaf(pv, hv.y, p.y);
                p.z = fmaf(pv, hv.z, p.z);
                p.w = fmaf(pv, hv.w, p.w);
            }
        }
    }
    const float4* tf = (const float4*)(tab + (size_t)(seg * 64 + c4) * 2);
    float4 t0 = tf[0], t1 = tf[1];
    float4 xo;
    xo.x = p.x * fmaf(t0.x, dgv, t0.y);
    xo.y = p.y * fmaf(t0.z, dgv, t0.w);
    xo.z = p.z * fmaf(t1.x, dgv, t1.y);
    xo.w = p.w * fmaf(t1.z, dgv, t1.w);
    if (last) {
        *(float4*)(x + (size_t)n * 64 + c4) = xo;
    } else {
        ushort4 s;
        s.x = f32_to_bf16(xo.x); s.y = f32_to_bf16(xo.y);
        s.z = f32_to_bf16(xo.z); s.w = f32_to_bf16(xo.w);
        *(ushort4*)(xbo + (size_t)n * 64 + c4) = s;
    }
}

// ---------------------------------------------------------------------------
__global__ __launch_bounds__(256) void k_gpool(const float* __restrict__ x,
                                               const int* __restrict__ batch,
                                               float* __restrict__ out,
                                               float* __restrict__ cnt) {
    int wave = (blockIdx.x * 256 + threadIdx.x) >> 6;
    int lane = threadIdx.x & 63;
    int n0 = wave * 64;
    if (n0 >= N_NODES) return;
    int n1 = min(n0 + 64, N_NODES);
    int g = batch[n0];
    float s = 0.f, c = 0.f;
    for (int n = n0; n < n1; ++n) {
        int gn = batch[n];
        if (gn != g) {
            atomicAdd(out + (size_t)g * 64 + lane, s);
            if (lane == 0) atomicAdd(cnt + g, c);
            s = 0.f; c = 0.f; g = gn;
        }
        s += x[(size_t)n * 64 + lane];
        c += 1.f;
    }
    atomicAdd(out + (size_t)g * 64 + lane, s);
    if (lane == 0) atomicAdd(cnt + g, c);
}

__global__ __launch_bounds__(256) void k_gdiv(float* __restrict__ out,
                                              const float* __restrict__ cnt) {
    int idx = blockIdx.x * 256 + threadIdx.x;
    if (idx >= G_ * 64) return;
    out[idx] /= fmaxf(cnt[idx >> 6], 1.f);
}

// ---------------------------------------------------------------------------
extern "C" void kernel_launch(void* const* d_in, const int* in_sizes, int n_in,
                              void* d_out, int out_size, void* d_ws, size_t ws_size,
                              hipStream_t stream) {
    const float* node_feat = (const float*)d_in[0];
    const float* degs      = (const float*)d_in[1];
    const int*   batch     = (const int*)  d_in[2];
    const int*   n2p_col   = (const int*)  d_in[4];
    const float* n2p_val   = (const float*)d_in[5];
    const float* e2p_val   = (const float*)d_in[8];
    const int*   pool_row  = (const int*)  d_in[9];
    const float* pool_val  = (const float*)d_in[11];
    const float* atom_W    = (const float*)d_in[12];
    const float* atom_b    = (const float*)d_in[13];
    const float* edge_W    = (const float*)d_in[14];
    const float* edge_b    = (const float*)d_in[15];
    const float* W_lrp     = (const float*)d_in[16];
    const float* b_lrp     = (const float*)d_in[17];
    const float* dn0_W     = (const float*)d_in[18];
    const float* dn0_b     = (const float*)d_in[19];
    const float* dn1_W     = (const float*)d_in[20];
    const float* dn1_b     = (const float*)d_in[21];

    char* ws = (char*)d_ws;
    float*          h      = (float*)         (ws);                 // 25,600,000
    unsigned short* xb     = (unsigned short*)(ws + 25600000);      // 12,800,000
    unsigned short* Wth    = (unsigned short*)(ws + 38400000);      //    524,288
    unsigned short* Wtl    = (unsigned short*)(ws + 38924288);      //    524,288
    int*            bucket = (int*)           (ws + 39448576);      //  8,000,000
    int*            cntn   = (int*)           (ws + 47448576);      //    400,000
    int*            ovf    = (int*)           (ws + 47848576);      //     16,384
    int*            ovfc   = (int*)           (ws + 47864960);      //        128
    float*          tab    = (float*)         (ws + 47865088);      //    264,192
    float*          thr    = (float*)         (ws + 48129280);      //      2,048
    float*          cntg   = (float*)         (ws + 48131328);      //      4,096
    float*          x      = (float*)         (ws + 48135424);      // 25,600,000

    hipLaunchKernelGGL(k_prep_w, dim3(1024), dim3(256), 0, stream, W_lrp, Wth, Wtl);
    hipLaunchKernelGGL(k_prep_factor, dim3(4), dim3(128), 0, stream,
                       dn0_W, dn0_b, dn1_W, dn1_b, tab, thr);
    hipLaunchKernelGGL(k_atom, dim3(25000), dim3(256), 0, stream,
                       node_feat, atom_W, atom_b, xb);
    hipMemsetAsync(cntn, 0, 400000, stream);
    hipMemsetAsync(ovfc, 0, 128, stream);
    hipLaunchKernelGGL(k_bucket, dim3(391), dim3(256), 0, stream,
                       pool_row, cntn, bucket, ovf, ovfc);
    for (int i = 0; i < 4; ++i) {
        hipLaunchKernelGGL(k_lrp, dim3(782), dim3(256), 0, stream,
                           xb, n2p_col, n2p_val, e2p_val, edge_W, edge_b,
                           Wth + (size_t)i * 65536, Wtl + (size_t)i * 65536,
                           b_lrp + i * 64, h);
        hipLaunchKernelGGL(k_pool_seg, dim3(6250), dim3(256), 0, stream,
                           h, cntn, bucket, ovf, ovfc, pool_row, pool_val,
                           degs, tab + (size_t)i * 129 * 128, thr + i * 128,
                           x, xb, (i == 3) ? 1 : 0);
    }
    hipMemsetAsync(d_out, 0, (size_t)G_ * 64 * 4, stream);
    hipMemsetAsync(cntg, 0, G_ * 4, stream);
    hipLaunchKernelGGL(k_gpool, dim3(391), dim3(256), 0, stream,
                       x, batch, (float*)d_out, cntg);
    hipLaunchKernelGGL(k_gdiv, dim3(256), dim3(256), 0, stream,
                       (float*)d_out, cntg);
}

// Round 9
// 596.911 us; speedup vs baseline: 3.0728x; 3.0728x over previous
//
#include <hip/hip_runtime.h>

typedef __attribute__((ext_vector_type(8))) short bf16x8;
typedef __attribute__((ext_vector_type(4))) float f32x4;

#define N_NODES   100000
#define NPERM_    100000
#define L_        16
#define G_        1024
#define CAP_      20
#define OVF_MAX   4096

__device__ inline unsigned short f32_to_bf16(float f) {
    unsigned u = __float_as_uint(f);
    unsigned r = (u + 0x7fff + ((u >> 16) & 1)) >> 16;   // RNE
    return (unsigned short)r;
}
__device__ inline float bflo(unsigned u) { return __uint_as_float(u << 16); }
__device__ inline float bfhi(unsigned u) { return __uint_as_float(u & 0xffff0000u); }
__device__ inline unsigned pk2(float a, float b) {
    return (unsigned)f32_to_bf16(a) | ((unsigned)f32_to_bf16(b) << 16);
}

// ---------------------------------------------------------------------------
// W_lrp [4][64 k][64 c][16 l] -> split bf16 (hi + residual), [4][16 l][64 c][64 k]
__global__ __launch_bounds__(256) void k_prep_w(const float* __restrict__ W,
                                                unsigned short* __restrict__ Wh,
                                                unsigned short* __restrict__ Wl) {
    int o = blockIdx.x * 256 + threadIdx.x;   // 262144
    int k = o & 63, c = (o >> 6) & 63, l = (o >> 12) & 15, i = o >> 16;
    float f = W[(((i * 64 + k) * 64) + c) * 16 + l];
    unsigned short hh = f32_to_bf16(f);
    float fl = f - __uint_as_float(((unsigned)hh) << 16);
    Wh[o] = hh;
    Wl[o] = f32_to_bf16(fl);
}

// ---------------------------------------------------------------------------
// factor[n,c] = relu(degs[n]*A + B) @ W1 + b1 is piecewise-linear in degs[n].
// Parallel build: grid (layer, seg-chunk); W1 layer staged in LDS; each
// thread evaluates the active set directly at a per-segment representative g.
__global__ __launch_bounds__(256) void k_prep_factor(const float* __restrict__ dn0_W,
                                                     const float* __restrict__ dn0_b,
                                                     const float* __restrict__ dn1_W,
                                                     const float* __restrict__ dn1_b,
                                                     float* __restrict__ tab,   // [4][129][64][2]
                                                     float* __restrict__ thr) { // [4][128]
    int i     = blockIdx.x;      // layer
    int chunk = blockIdx.y;      // seg chunk (17 segs each, 8 chunks)
    int tid   = threadIdx.x;
    __shared__ float A[128], B[128], ts[128], tv[128];
    __shared__ float W1l[128 * 64];
    if (tid < 128) { A[tid] = dn0_W[i * 128 + tid]; B[tid] = dn0_b[i * 128 + tid]; }
    {
        const float4* src = (const float4*)(dn1_W + (size_t)i * 8192);
        float4*       dst = (float4*)W1l;
        for (int t = tid; t < 2048; t += 256) dst[t] = src[t];
    }
    __syncthreads();
    if (tid < 128) {
        float a = A[tid], b = B[tid];
        float tj = -b / a;
        if (a == 0.f || !(tj > 0.f)) tj = 1e30f;   // no crossing in (0, inf)
        tv[tid] = tj;
    }
    __syncthreads();
    if (tid < 128) {
        float tj = tv[tid];
        int rank = 0;
        for (int j = 0; j < 128; ++j) {
            float o = tv[j];
            rank += (o < tj) || (o == tj && j < tid);
        }
        ts[rank] = tj;
    }
    __syncthreads();
    if (chunk == 0 && tid < 128) thr[i * 128 + tid] = ts[tid];
    int s0 = chunk * 17;
    int s1 = min(s0 + 17, 129);
    float* tb = tab + (size_t)i * 129 * 128;
    for (int item = s0 * 64 + tid; item < s1 * 64; item += 256) {
        int s = item >> 6;
        int c = item & 63;
        float lo = (s == 0) ? 0.f : ts[s - 1];
        float hi = (s == 128) ? 1e30f : ts[s];
        float g;
        if (lo > 1e29f)       g = 1e29f;        // unreachable segment
        else if (hi > 1e29f)  g = lo + 1.f;     // unbounded: any g > lo
        else                  g = 0.5f * (lo + hi);
        float alpha = 0.f, beta = dn1_b[i * 64 + c];
        for (int j = 0; j < 128; ++j) {
            if (fmaf(g, A[j], B[j]) > 0.f) {
                float w1 = W1l[j * 64 + c];
                alpha = fmaf(A[j], w1, alpha);
                beta  = fmaf(B[j], w1, beta);
            }
        }
        tb[s * 128 + c * 2 + 0] = alpha;
        tb[s * 128 + c * 2 + 1] = beta;
    }
}

// ---------------------------------------------------------------------------
// xb = bf16(node_feat @ atom_W + atom_b)
__global__ __launch_bounds__(256) void k_atom(const float* __restrict__ feat,
                                              const float* __restrict__ W,
                                              const float* __restrict__ b,
                                              unsigned short* __restrict__ xb) {
    __shared__ float Wlds[28 * 64];
    __shared__ float blds[64];
    int tid = threadIdx.x;
    for (int t = tid; t < 28 * 64; t += 256) Wlds[t] = W[t];
    if (tid < 64) blds[tid] = b[tid];
    __syncthreads();
    int n = blockIdx.x * 4 + (tid >> 6);
    int c = tid & 63;
    if (n >= N_NODES) return;
    const float* fr = feat + n * 28;
    float acc = blds[c];
#pragma unroll
    for (int j = 0; j < 28; ++j) acc = fmaf(fr[j], Wlds[j * 64 + c], acc);
    xb[n * 64 + c] = f32_to_bf16(acc);
}

// ---------------------------------------------------------------------------
__global__ __launch_bounds__(256) void k_bucket(const int* __restrict__ prow,
                                                int* __restrict__ cntn,
                                                int* __restrict__ bucket,
                                                int* __restrict__ ovf,
                                                int* __restrict__ ovfc) {
    int d = blockIdx.x * 256 + threadIdx.x;
    if (d >= NPERM_) return;
    int n = prow[d];
    int s = atomicAdd(cntn + n, 1);
    if (s < CAP_) bucket[n * CAP_ + s] = d;
    else { int o = atomicAdd(ovfc, 1); if (o < OVF_MAX) ovf[o] = d; }
}

// ---------------------------------------------------------------------------
// MFMA gather-GEMM:  h = relu( T(gather,bf16) @ (Whi+Wlo) + b )
// 2-phase-deep x-row pipeline (xvA/xvB ping-pong), LDS-bounce clean C-write.
__global__ __launch_bounds__(256, 4) void k_lrp(const unsigned short* __restrict__ xbuf,
                                                const int*   __restrict__ n2p_col,
                                                const float* __restrict__ n2p_val,
                                                const float* __restrict__ e2p_val,
                                                const float* __restrict__ edge_W,
                                                const float* __restrict__ edge_b,
                                                const unsigned short* __restrict__ Wth, // [16][64][64]
                                                const unsigned short* __restrict__ Wtl,
                                                const float* __restrict__ bl,
                                                float* __restrict__ hout) {
    __shared__ unsigned short Tb[128][72];
    __shared__ unsigned short Wh[64][72];
    __shared__ unsigned short Wo[64][72];
    __shared__ float efs[64];
    int tid = threadIdx.x;
    int lane = tid & 63;
    int w = tid >> 6;
    int d0 = blockIdx.x * 128;
    int dl = tid >> 1;
    int kq = tid & 1;
    int wc = tid >> 2;
    int wk = (tid & 3) * 16;
    int dg = d0 + dl;
    int dsafe = (dg < NPERM_) ? dg : 0;
    size_t pbase = (size_t)dsafe * 16;

    if (tid < 64) efs[tid] = edge_W[tid] + edge_b[tid];

    f32x4 acc[2][4];
#pragma unroll
    for (int aa = 0; aa < 2; ++aa)
#pragma unroll
        for (int cb = 0; cb < 4; ++cb) acc[aa][cb] = (f32x4)0.f;

    uint4 xvA[4], xvB[4], wvh0, wvh1, wvl0, wvl1;
    int   colN  = n2p_col[pbase + 2];
    int   colN2 = n2p_col[pbase + 3];
    float vnN   = n2p_val[pbase + 0];
    float veN   = e2p_val[pbase + 0];
    {
        int c0 = n2p_col[pbase + 0];
        int c1 = n2p_col[pbase + 1];
        const uint4* xr0 = (const uint4*)(xbuf + (size_t)c0 * 64 + kq * 32);
#pragma unroll
        for (int j = 0; j < 4; ++j) xvA[j] = xr0[j];
        const uint4* xr1 = (const uint4*)(xbuf + (size_t)c1 * 64 + kq * 32);
#pragma unroll
        for (int j = 0; j < 4; ++j) xvB[j] = xr1[j];
        const uint4* whr = (const uint4*)(Wth + wc * 64 + wk);
        wvh0 = whr[0]; wvh1 = whr[1];
        const uint4* wlr = (const uint4*)(Wtl + wc * 64 + wk);
        wvl0 = wlr[0]; wvl1 = wlr[1];
    }
    __syncthreads();   // efs visible

#define LRP_PHASE(LVAL, XV)                                                      \
    {                                                                            \
        const int l = (LVAL);                                                    \
        float vn = vnN, ve = veN;                                                \
        __syncthreads();                                                         \
        _Pragma("unroll")                                                        \
        for (int j = 0; j < 4; ++j) {                                            \
            uint4 v = XV[j];                                                     \
            int kb = kq * 32 + j * 8;                                            \
            float4 ea = *(const float4*)&efs[kb];                                \
            float4 eb = *(const float4*)&efs[kb + 4];                            \
            float t0 = fmaf(vn, bflo(v.x), ve * ea.x);                           \
            float t1 = fmaf(vn, bfhi(v.x), ve * ea.y);                           \
            float t2 = fmaf(vn, bflo(v.y), ve * ea.z);                           \
            float t3 = fmaf(vn, bfhi(v.y), ve * ea.w);                           \
            float t4 = fmaf(vn, bflo(v.z), ve * eb.x);                           \
            float t5 = fmaf(vn, bfhi(v.z), ve * eb.y);                           \
            float t6 = fmaf(vn, bflo(v.w), ve * eb.z);                           \
            float t7 = fmaf(vn, bfhi(v.w), ve * eb.w);                           \
            uint4 ow;                                                            \
            ow.x = pk2(t0, t1); ow.y = pk2(t2, t3);                              \
            ow.z = pk2(t4, t5); ow.w = pk2(t6, t7);                              \
            *(uint4*)&Tb[dl][kb] = ow;                                           \
        }                                                                        \
        *(uint4*)&Wh[wc][wk]     = wvh0;                                         \
        *(uint4*)&Wh[wc][wk + 8] = wvh1;                                         \
        *(uint4*)&Wo[wc][wk]     = wvl0;                                         \
        *(uint4*)&Wo[wc][wk + 8] = wvl1;                                         \
        __syncthreads();                                                         \
        if (l < 15) {                                                            \
            const uint4* whr = (const uint4*)(Wth + (l + 1) * 4096 + wc * 64 + wk); \
            wvh0 = whr[0]; wvh1 = whr[1];                                        \
            const uint4* wlr = (const uint4*)(Wtl + (l + 1) * 4096 + wc * 64 + wk); \
            wvl0 = wlr[0]; wvl1 = wlr[1];                                        \
            vnN = n2p_val[pbase + l + 1];                                        \
            veN = e2p_val[pbase + l + 1];                                        \
        }                                                                        \
        if (l < 14) {   /* issue row for l+2 into just-consumed buffer */        \
            const uint4* xr = (const uint4*)(xbuf + (size_t)colN * 64 + kq * 32);\
            _Pragma("unroll")                                                    \
            for (int j = 0; j < 4; ++j) XV[j] = xr[j];                           \
            colN = colN2;                                                        \
            if (l < 12) colN2 = n2p_col[pbase + l + 4];                          \
        }                                                                        \
        {                                                                        \
            int r = lane & 15, q = lane >> 4;                                    \
            _Pragma("unroll")                                                    \
            for (int s = 0; s < 2; ++s) {                                        \
                int ko = s * 32 + q * 8;                                         \
                bf16x8 a0 = *(const bf16x8*)&Tb[w * 32 + r][ko];                 \
                bf16x8 a1 = *(const bf16x8*)&Tb[w * 32 + 16 + r][ko];            \
                _Pragma("unroll")                                                \
                for (int cb = 0; cb < 4; ++cb) {                                 \
                    bf16x8 bh = *(const bf16x8*)&Wh[cb * 16 + r][ko];            \
                    bf16x8 bo = *(const bf16x8*)&Wo[cb * 16 + r][ko];            \
                    acc[0][cb] = __builtin_amdgcn_mfma_f32_16x16x32_bf16(a0, bh, acc[0][cb], 0, 0, 0); \
                    acc[0][cb] = __builtin_amdgcn_mfma_f32_16x16x32_bf16(a0, bo, acc[0][cb], 0, 0, 0); \
                    acc[1][cb] = __builtin_amdgcn_mfma_f32_16x16x32_bf16(a1, bh, acc[1][cb], 0, 0, 0); \
                    acc[1][cb] = __builtin_amdgcn_mfma_f32_16x16x32_bf16(a1, bo, acc[1][cb], 0, 0, 0); \
                }                                                                \
            }                                                                    \
        }                                                                        \
    }

#pragma unroll 1
    for (int lp = 0; lp < 8; ++lp) {
        LRP_PHASE(2 * lp,     xvA)
        LRP_PHASE(2 * lp + 1, xvB)
    }
#undef LRP_PHASE

    // epilogue: bias+relu, bounce through per-wave LDS slice, clean float4 rows
    __syncthreads();   // all MFMA reads of Tb done
    {
        int r = lane & 15, q = lane >> 4;
        float* F = (float*)(&Tb[0][0]) + w * 1024;   // 4 KB per wave
#pragma unroll
        for (int aa = 0; aa < 2; ++aa) {
#pragma unroll
            for (int cb = 0; cb < 4; ++cb) {
                float bias = bl[cb * 16 + r];
#pragma unroll
                for (int reg = 0; reg < 4; ++reg)
                    F[(q * 4 + reg) * 64 + cb * 16 + r] = fmaxf(acc[aa][cb][reg] + bias, 0.f);
            }
#pragma unroll
            for (int ii = 0; ii < 4; ++ii) {
                int idx = lane + ii * 64;            // 0..255 -> 16 rows x 16 float4
                float4 v = ((const float4*)F)[idx];
                int R = d0 + w * 32 + aa * 16 + (idx >> 4);
                if (R < NPERM_)
                    *(float4*)(hout + (size_t)R * 64 + (idx & 15) * 4) = v;
            }
        }
    }
}

// ---------------------------------------------------------------------------
// x[n] = (bucket-gather pool of h) * (alpha[seg]*degs + beta[seg])
// last=0: write bf16 shadow only;  last=1: write f32 x only.
__global__ __launch_bounds__(256) void k_pool_seg(const float* __restrict__ h,
                                                  const int*   __restrict__ cntn,
                                                  const int*   __restrict__ bucket,
                                                  const int*   __restrict__ ovf,
                                                  const int*   __restrict__ ovfc,
                                                  const int*   __restrict__ prow,
                                                  const float* __restrict__ pval,
                                                  const float* __restrict__ degs,
                                                  const float* __restrict__ tab,  // [129][64][2]
                                                  const float* __restrict__ thr,  // [128]
                                                  float* __restrict__ x,
                                                  unsigned short* __restrict__ xbo,
                                                  int last) {
    __shared__ float thrl[128];
    int tid = threadIdx.x;
    if (tid < 128) thrl[tid] = thr[tid];
    __syncthreads();
    int n  = blockIdx.x * 16 + (tid >> 4);
    int c4 = (tid & 15) * 4;
    if (n >= N_NODES) return;
    float dgv = degs[n];
    int seg = 0;
    if (thrl[63]       < dgv) seg = 64;
    if (thrl[seg + 31] < dgv) seg += 32;
    if (thrl[seg + 15] < dgv) seg += 16;
    if (thrl[seg + 7]  < dgv) seg += 8;
    if (thrl[seg + 3]  < dgv) seg += 4;
    if (thrl[seg + 1]  < dgv) seg += 2;
    if (thrl[seg]      < dgv) seg += 1;
    float4 p = make_float4(0.f, 0.f, 0.f, 0.f);
    int cn = min(cntn[n], CAP_);
    for (int j = 0; j < cn; ++j) {
        int   d  = bucket[n * CAP_ + j];
        float pv = pval[d];
        float4 hv = *(const float4*)(h + (size_t)d * 64 + c4);
        p.x = fmaf(pv, hv.x, p.x);
        p.y = fmaf(pv, hv.y, p.y);
        p.z = fmaf(pv, hv.z, p.z);
        p.w = fmaf(pv, hv.w, p.w);
    }
    int novf = *ovfc;
    if (novf > 0) {
        int ne = novf < OVF_MAX ? novf : OVF_MAX;
        for (int e = 0; e < ne; ++e) {
            int d = ovf[e];
            if (prow[d] == n) {
                float pv = pval[d];
                float4 hv = *(const float4*)(h + (size_t)d * 64 + c4);
                p.x = fmaf(pv, hv.x, p.x);
                p.y = fmaf(pv, hv.y, p.y);
                p.z = fmaf(pv, hv.z, p.z);
                p.w = fmaf(pv, hv.w, p.w);
            }
        }
    }
    const float4* tf = (const float4*)(tab + (size_t)(seg * 64 + c4) * 2);
    float4 t0 = tf[0], t1 = tf[1];
    float4 xo;
    xo.x = p.x * fmaf(t0.x, dgv, t0.y);
    xo.y = p.y * fmaf(t0.z, dgv, t0.w);
    xo.z = p.z * fmaf(t1.x, dgv, t1.y);
    xo.w = p.w * fmaf(t1.z, dgv, t1.w);
    if (last) {
        *(float4*)(x + (size_t)n * 64 + c4) = xo;
    } else {
        ushort4 s;
        s.x = f32_to_bf16(xo.x); s.y = f32_to_bf16(xo.y);
        s.z = f32_to_bf16(xo.z); s.w = f32_to_bf16(xo.w);
        *(ushort4*)(xbo + (size_t)n * 64 + c4) = s;
    }
}

// ---------------------------------------------------------------------------
__global__ __launch_bounds__(256) void k_gpool(const float* __restrict__ x,
                                               const int* __restrict__ batch,
                                               float* __restrict__ out,
                                               float* __restrict__ cnt) {
    int wave = (blockIdx.x * 256 + threadIdx.x) >> 6;
    int lane = threadIdx.x & 63;
    int n0 = wave * 64;
    if (n0 >= N_NODES) return;
    int n1 = min(n0 + 64, N_NODES);
    int g = batch[n0];
    float s = 0.f, c = 0.f;
    for (int n = n0; n < n1; ++n) {
        int gn = batch[n];
        if (gn != g) {
            atomicAdd(out + (size_t)g * 64 + lane, s);
            if (lane == 0) atomicAdd(cnt + g, c);
            s = 0.f; c = 0.f; g = gn;
        }
        s += x[(size_t)n * 64 + lane];
        c += 1.f;
    }
    atomicAdd(out + (size_t)g * 64 + lane, s);
    if (lane == 0) atomicAdd(cnt + g, c);
}

__global__ __launch_bounds__(256) void k_gdiv(float* __restrict__ out,
                                              const float* __restrict__ cnt) {
    int idx = blockIdx.x * 256 + threadIdx.x;
    if (idx >= G_ * 64) return;
    out[idx] /= fmaxf(cnt[idx >> 6], 1.f);
}

// ---------------------------------------------------------------------------
extern "C" void kernel_launch(void* const* d_in, const int* in_sizes, int n_in,
                              void* d_out, int out_size, void* d_ws, size_t ws_size,
                              hipStream_t stream) {
    const float* node_feat = (const float*)d_in[0];
    const float* degs      = (const float*)d_in[1];
    const int*   batch     = (const int*)  d_in[2];
    const int*   n2p_col   = (const int*)  d_in[4];
    const float* n2p_val   = (const float*)d_in[5];
    const float* e2p_val   = (const float*)d_in[8];
    const int*   pool_row  = (const int*)  d_in[9];
    const float* pool_val  = (const float*)d_in[11];
    const float* atom_W    = (const float*)d_in[12];
    const float* atom_b    = (const float*)d_in[13];
    const float* edge_W    = (const float*)d_in[14];
    const float* edge_b    = (const float*)d_in[15];
    const float* W_lrp     = (const float*)d_in[16];
    const float* b_lrp     = (const float*)d_in[17];
    const float* dn0_W     = (const float*)d_in[18];
    const float* dn0_b     = (const float*)d_in[19];
    const float* dn1_W     = (const float*)d_in[20];
    const float* dn1_b     = (const float*)d_in[21];

    char* ws = (char*)d_ws;
    float*          h      = (float*)         (ws);                 // 25,600,000
    unsigned short* xb     = (unsigned short*)(ws + 25600000);      // 12,800,000
    unsigned short* Wth    = (unsigned short*)(ws + 38400000);      //    524,288
    unsigned short* Wtl    = (unsigned short*)(ws + 38924288);      //    524,288
    int*            bucket = (int*)           (ws + 39448576);      //  8,000,000
    int*            cntn   = (int*)           (ws + 47448576);      //    400,000
    int*            ovf    = (int*)           (ws + 47848576);      //     16,384
    int*            ovfc   = (int*)           (ws + 47864960);      //        128
    float*          tab    = (float*)         (ws + 47865088);      //    264,192
    float*          thr    = (float*)         (ws + 48129280);      //      2,048
    float*          cntg   = (float*)         (ws + 48131328);      //      4,096
    float*          x      = (float*)         (ws + 48135424);      // 25,600,000

    hipLaunchKernelGGL(k_prep_w, dim3(1024), dim3(256), 0, stream, W_lrp, Wth, Wtl);
    hipLaunchKernelGGL(k_prep_factor, dim3(4, 8), dim3(256), 0, stream,
                       dn0_W, dn0_b, dn1_W, dn1_b, tab, thr);
    hipLaunchKernelGGL(k_atom, dim3(25000), dim3(256), 0, stream,
                       node_feat, atom_W, atom_b, xb);
    hipMemsetAsync(cntn, 0, 400000, stream);
    hipMemsetAsync(ovfc, 0, 128, stream);
    hipLaunchKernelGGL(k_bucket, dim3(391), dim3(256), 0, stream,
                       pool_row, cntn, bucket, ovf, ovfc);
    for (int i = 0; i < 4; ++i) {
        hipLaunchKernelGGL(k_lrp, dim3(782), dim3(256), 0, stream,
                           xb, n2p_col, n2p_val, e2p_val, edge_W, edge_b,
                           Wth + (size_t)i * 65536, Wtl + (size_t)i * 65536,
                           b_lrp + i * 64, h);
        hipLaunchKernelGGL(k_pool_seg, dim3(6250), dim3(256), 0, stream,
                           h, cntn, bucket, ovf, ovfc, pool_row, pool_val,
                           degs, tab + (size_t)i * 129 * 128, thr + i * 128,
                           x, xb, (i == 3) ? 1 : 0);
    }
    hipMemsetAsync(d_out, 0, (size_t)G_ * 64 * 4, stream);
    hipMemsetAsync(cntg, 0, G_ * 4, stream);
    hipLaunchKernelGGL(k_gpool, dim3(391), dim3(256), 0, stream,
                       x, batch, (float*)d_out, cntg);
    hipLaunchKernelGGL(k_gdiv, dim3(256), dim3(256), 0, stream,
                       (float*)d_out, cntg);
}

// Round 10
// 596.564 us; speedup vs baseline: 3.0746x; 1.0006x over previous
//
#include <hip/hip_runtime.h>

typedef __attribute__((ext_vector_type(8))) short bf16x8;
typedef __attribute__((ext_vector_type(4))) float f32x4;

#define N_NODES   100000
#define NPERM_    100000
#define L_        16
#define G_        1024
#define CAP_      20
#define OVF_MAX   4096

__device__ inline unsigned short f32_to_bf16(float f) {
    unsigned u = __float_as_uint(f);
    unsigned r = (u + 0x7fff + ((u >> 16) & 1)) >> 16;   // RNE
    return (unsigned short)r;
}
__device__ inline float bflo(unsigned u) { return __uint_as_float(u << 16); }
__device__ inline float bfhi(unsigned u) { return __uint_as_float(u & 0xffff0000u); }
__device__ inline float bfup(unsigned short s) { return __uint_as_float((unsigned)s << 16); }
__device__ inline unsigned pk2(float a, float b) {
    return (unsigned)f32_to_bf16(a) | ((unsigned)f32_to_bf16(b) << 16);
}

// ---------------------------------------------------------------------------
// W_lrp [4][64 k][64 c][16 l] -> split bf16 (hi + residual), [4][16 l][64 c][64 k]
__global__ __launch_bounds__(256) void k_prep_w(const float* __restrict__ W,
                                                unsigned short* __restrict__ Wh,
                                                unsigned short* __restrict__ Wl) {
    int o = blockIdx.x * 256 + threadIdx.x;   // 262144
    int k = o & 63, c = (o >> 6) & 63, l = (o >> 12) & 15, i = o >> 16;
    float f = W[(((i * 64 + k) * 64) + c) * 16 + l];
    unsigned short hh = f32_to_bf16(f);
    float fl = f - __uint_as_float(((unsigned)hh) << 16);
    Wh[o] = hh;
    Wl[o] = f32_to_bf16(fl);
}

// ---------------------------------------------------------------------------
// factor[n,c] = relu(degs[n]*A + B) @ W1 + b1 is piecewise-linear in degs[n].
// Parallel build: grid (layer, seg-chunk); W1 layer staged in LDS; each
// thread evaluates the active set directly at a per-segment representative g.
__global__ __launch_bounds__(256) void k_prep_factor(const float* __restrict__ dn0_W,
                                                     const float* __restrict__ dn0_b,
                                                     const float* __restrict__ dn1_W,
                                                     const float* __restrict__ dn1_b,
                                                     float* __restrict__ tab,   // [4][129][64][2]
                                                     float* __restrict__ thr) { // [4][128]
    int i     = blockIdx.x;      // layer
    int chunk = blockIdx.y;      // seg chunk (17 segs each, 8 chunks)
    int tid   = threadIdx.x;
    __shared__ float A[128], B[128], ts[128], tv[128];
    __shared__ float W1l[128 * 64];
    if (tid < 128) { A[tid] = dn0_W[i * 128 + tid]; B[tid] = dn0_b[i * 128 + tid]; }
    {
        const float4* src = (const float4*)(dn1_W + (size_t)i * 8192);
        float4*       dst = (float4*)W1l;
        for (int t = tid; t < 2048; t += 256) dst[t] = src[t];
    }
    __syncthreads();
    if (tid < 128) {
        float a = A[tid], b = B[tid];
        float tj = -b / a;
        if (a == 0.f || !(tj > 0.f)) tj = 1e30f;   // no crossing in (0, inf)
        tv[tid] = tj;
    }
    __syncthreads();
    if (tid < 128) {
        float tj = tv[tid];
        int rank = 0;
        for (int j = 0; j < 128; ++j) {
            float o = tv[j];
            rank += (o < tj) || (o == tj && j < tid);
        }
        ts[rank] = tj;
    }
    __syncthreads();
    if (chunk == 0 && tid < 128) thr[i * 128 + tid] = ts[tid];
    int s0 = chunk * 17;
    int s1 = min(s0 + 17, 129);
    float* tb = tab + (size_t)i * 129 * 128;
    for (int item = s0 * 64 + tid; item < s1 * 64; item += 256) {
        int s = item >> 6;
        int c = item & 63;
        float lo = (s == 0) ? 0.f : ts[s - 1];
        float hi = (s == 128) ? 1e30f : ts[s];
        float g;
        if (lo > 1e29f)       g = 1e29f;        // unreachable segment
        else if (hi > 1e29f)  g = lo + 1.f;     // unbounded: any g > lo
        else                  g = 0.5f * (lo + hi);
        float alpha = 0.f, beta = dn1_b[i * 64 + c];
        for (int j = 0; j < 128; ++j) {
            if (fmaf(g, A[j], B[j]) > 0.f) {
                float w1 = W1l[j * 64 + c];
                alpha = fmaf(A[j], w1, alpha);
                beta  = fmaf(B[j], w1, beta);
            }
        }
        tb[s * 128 + c * 2 + 0] = alpha;
        tb[s * 128 + c * 2 + 1] = beta;
    }
}

// ---------------------------------------------------------------------------
// xb = bf16(node_feat @ atom_W + atom_b)
__global__ __launch_bounds__(256) void k_atom(const float* __restrict__ feat,
                                              const float* __restrict__ W,
                                              const float* __restrict__ b,
                                              unsigned short* __restrict__ xb) {
    __shared__ float Wlds[28 * 64];
    __shared__ float blds[64];
    int tid = threadIdx.x;
    for (int t = tid; t < 28 * 64; t += 256) Wlds[t] = W[t];
    if (tid < 64) blds[tid] = b[tid];
    __syncthreads();
    int n = blockIdx.x * 4 + (tid >> 6);
    int c = tid & 63;
    if (n >= N_NODES) return;
    const float* fr = feat + n * 28;
    float acc = blds[c];
#pragma unroll
    for (int j = 0; j < 28; ++j) acc = fmaf(fr[j], Wlds[j * 64 + c], acc);
    xb[n * 64 + c] = f32_to_bf16(acc);
}

// ---------------------------------------------------------------------------
__global__ __launch_bounds__(256) void k_bucket(const int* __restrict__ prow,
                                                int* __restrict__ cntn,
                                                int* __restrict__ bucket,
                                                int* __restrict__ ovf,
                                                int* __restrict__ ovfc) {
    int d = blockIdx.x * 256 + threadIdx.x;
    if (d >= NPERM_) return;
    int n = prow[d];
    int s = atomicAdd(cntn + n, 1);
    if (s < CAP_) bucket[n * CAP_ + s] = d;
    else { int o = atomicAdd(ovfc, 1); if (o < OVF_MAX) ovf[o] = d; }
}

// ---------------------------------------------------------------------------
// MFMA gather-GEMM:  h = relu( T(gather,bf16) @ (Whi+Wlo) + b ), h in bf16.
// 64-row blocks (4 waves x 16 rows) for occupancy; 2-phase x-row pipeline.
__global__ __launch_bounds__(256, 5) void k_lrp(const unsigned short* __restrict__ xbuf,
                                                const int*   __restrict__ n2p_col,
                                                const float* __restrict__ n2p_val,
                                                const float* __restrict__ e2p_val,
                                                const float* __restrict__ edge_W,
                                                const float* __restrict__ edge_b,
                                                const unsigned short* __restrict__ Wth, // [16][64][64]
                                                const unsigned short* __restrict__ Wtl,
                                                const float* __restrict__ bl,
                                                unsigned short* __restrict__ hout) {
    __shared__ unsigned short Tb[64][72];
    __shared__ unsigned short Wh[64][72];
    __shared__ unsigned short Wo[64][72];
    __shared__ float efs[64];
    int tid = threadIdx.x;
    int lane = tid & 63;
    int w = tid >> 6;
    int d0 = blockIdx.x * 64;
    int dl = tid >> 2;              // T-fill row 0..63
    int kq = tid & 3;               // T-fill k-quarter (16 bf16)
    int wc = tid >> 2;              // W-fill row (c)
    int wk = (tid & 3) * 16;        // W-fill k offset
    int dg = d0 + dl;
    int dsafe = (dg < NPERM_) ? dg : 0;
    size_t pbase = (size_t)dsafe * 16;

    if (tid < 64) efs[tid] = edge_W[tid] + edge_b[tid];

    f32x4 acc[4];
#pragma unroll
    for (int cb = 0; cb < 4; ++cb) acc[cb] = (f32x4)0.f;

    uint4 xvA[2], xvB[2], wvh0, wvh1, wvl0, wvl1;
    int   colN  = n2p_col[pbase + 2];
    int   colN2 = n2p_col[pbase + 3];
    float vnN   = n2p_val[pbase + 0];
    float veN   = e2p_val[pbase + 0];
    {
        int c0 = n2p_col[pbase + 0];
        int c1 = n2p_col[pbase + 1];
        const uint4* xr0 = (const uint4*)(xbuf + (size_t)c0 * 64 + kq * 16);
        xvA[0] = xr0[0]; xvA[1] = xr0[1];
        const uint4* xr1 = (const uint4*)(xbuf + (size_t)c1 * 64 + kq * 16);
        xvB[0] = xr1[0]; xvB[1] = xr1[1];
        const uint4* whr = (const uint4*)(Wth + wc * 64 + wk);
        wvh0 = whr[0]; wvh1 = whr[1];
        const uint4* wlr = (const uint4*)(Wtl + wc * 64 + wk);
        wvl0 = wlr[0]; wvl1 = wlr[1];
    }
    __syncthreads();   // efs visible

#define LRP_PHASE(LVAL, XV)                                                      \
    {                                                                            \
        const int l = (LVAL);                                                    \
        float vn = vnN, ve = veN;                                                \
        __syncthreads();                                                         \
        _Pragma("unroll")                                                        \
        for (int j = 0; j < 2; ++j) {                                            \
            uint4 v = XV[j];                                                     \
            int kb = kq * 16 + j * 8;                                            \
            float4 ea = *(const float4*)&efs[kb];                                \
            float4 eb = *(const float4*)&efs[kb + 4];                            \
            float t0 = fmaf(vn, bflo(v.x), ve * ea.x);                           \
            float t1 = fmaf(vn, bfhi(v.x), ve * ea.y);                           \
            float t2 = fmaf(vn, bflo(v.y), ve * ea.z);                           \
            float t3 = fmaf(vn, bfhi(v.y), ve * ea.w);                           \
            float t4 = fmaf(vn, bflo(v.z), ve * eb.x);                           \
            float t5 = fmaf(vn, bfhi(v.z), ve * eb.y);                           \
            float t6 = fmaf(vn, bflo(v.w), ve * eb.z);                           \
            float t7 = fmaf(vn, bfhi(v.w), ve * eb.w);                           \
            uint4 ow;                                                            \
            ow.x = pk2(t0, t1); ow.y = pk2(t2, t3);                              \
            ow.z = pk2(t4, t5); ow.w = pk2(t6, t7);                              \
            *(uint4*)&Tb[dl][kb] = ow;                                           \
        }                                                                        \
        *(uint4*)&Wh[wc][wk]     = wvh0;                                         \
        *(uint4*)&Wh[wc][wk + 8] = wvh1;                                         \
        *(uint4*)&Wo[wc][wk]     = wvl0;                                         \
        *(uint4*)&Wo[wc][wk + 8] = wvl1;                                         \
        __syncthreads();                                                         \
        if (l < 15) {                                                            \
            const uint4* whr = (const uint4*)(Wth + (l + 1) * 4096 + wc * 64 + wk); \
            wvh0 = whr[0]; wvh1 = whr[1];                                        \
            const uint4* wlr = (const uint4*)(Wtl + (l + 1) * 4096 + wc * 64 + wk); \
            wvl0 = wlr[0]; wvl1 = wlr[1];                                        \
            vnN = n2p_val[pbase + l + 1];                                        \
            veN = e2p_val[pbase + l + 1];                                        \
        }                                                                        \
        if (l < 14) {   /* issue row for l+2 into just-consumed buffer */        \
            const uint4* xr = (const uint4*)(xbuf + (size_t)colN * 64 + kq * 16);\
            XV[0] = xr[0]; XV[1] = xr[1];                                        \
            colN = colN2;                                                        \
            if (l < 12) colN2 = n2p_col[pbase + l + 4];                          \
        }                                                                        \
        {                                                                        \
            int r = lane & 15, q = lane >> 4;                                    \
            _Pragma("unroll")                                                    \
            for (int s = 0; s < 2; ++s) {                                        \
                int ko = s * 32 + q * 8;                                         \
                bf16x8 a0 = *(const bf16x8*)&Tb[w * 16 + r][ko];                 \
                _Pragma("unroll")                                                \
                for (int cb = 0; cb < 4; ++cb) {                                 \
                    bf16x8 bh = *(const bf16x8*)&Wh[cb * 16 + r][ko];            \
                    bf16x8 bo = *(const bf16x8*)&Wo[cb * 16 + r][ko];            \
                    acc[cb] = __builtin_amdgcn_mfma_f32_16x16x32_bf16(a0, bh, acc[cb], 0, 0, 0); \
                    acc[cb] = __builtin_amdgcn_mfma_f32_16x16x32_bf16(a0, bo, acc[cb], 0, 0, 0); \
                }                                                                \
            }                                                                    \
        }                                                                        \
    }

#pragma unroll 1
    for (int lp = 0; lp < 8; ++lp) {
        LRP_PHASE(2 * lp,     xvA)
        LRP_PHASE(2 * lp + 1, xvB)
    }
#undef LRP_PHASE

    // epilogue: bias+relu -> bf16, bounce through per-wave LDS, clean 16B rows
    __syncthreads();   // all MFMA reads of Tb done
    {
        int r = lane & 15, q = lane >> 4;
        unsigned short* F = &Tb[0][0] + w * 1024;   // 16x64 bf16 = 2 KB per wave
#pragma unroll
        for (int cb = 0; cb < 4; ++cb) {
            float bias = bl[cb * 16 + r];
#pragma unroll
            for (int reg = 0; reg < 4; ++reg)
                F[(q * 4 + reg) * 64 + cb * 16 + r] =
                    f32_to_bf16(fmaxf(acc[cb][reg] + bias, 0.f));
        }
#pragma unroll
        for (int ii = 0; ii < 2; ++ii) {
            int idx = lane + ii * 64;               // 0..127: 16 rows x 8 uint4
            uint4 v = ((const uint4*)F)[idx];
            int R = d0 + w * 16 + (idx >> 3);
            if (R < NPERM_)
                *(uint4*)(hout + (size_t)R * 64 + (idx & 7) * 8) = v;
        }
    }
}

// ---------------------------------------------------------------------------
// x[n] = (bucket-gather pool of bf16 h) * (alpha[seg]*degs + beta[seg])
// last=0: write bf16 shadow only;  last=1: write f32 x only.
__global__ __launch_bounds__(256) void k_pool_seg(const unsigned short* __restrict__ h,
                                                  const int*   __restrict__ cntn,
                                                  const int*   __restrict__ bucket,
                                                  const int*   __restrict__ ovf,
                                                  const int*   __restrict__ ovfc,
                                                  const int*   __restrict__ prow,
                                                  const float* __restrict__ pval,
                                                  const float* __restrict__ degs,
                                                  const float* __restrict__ tab,  // [129][64][2]
                                                  const float* __restrict__ thr,  // [128]
                                                  float* __restrict__ x,
                                                  unsigned short* __restrict__ xbo,
                                                  int last) {
    __shared__ float thrl[128];
    int tid = threadIdx.x;
    if (tid < 128) thrl[tid] = thr[tid];
    __syncthreads();
    int n  = blockIdx.x * 16 + (tid >> 4);
    int c4 = (tid & 15) * 4;
    if (n >= N_NODES) return;
    float dgv = degs[n];
    int seg = 0;
    if (thrl[63]       < dgv) seg = 64;
    if (thrl[seg + 31] < dgv) seg += 32;
    if (thrl[seg + 15] < dgv) seg += 16;
    if (thrl[seg + 7]  < dgv) seg += 8;
    if (thrl[seg + 3]  < dgv) seg += 4;
    if (thrl[seg + 1]  < dgv) seg += 2;
    if (thrl[seg]      < dgv) seg += 1;
    float4 p = make_float4(0.f, 0.f, 0.f, 0.f);
    int cn = min(cntn[n], CAP_);
    for (int j = 0; j < cn; ++j) {
        int   d  = bucket[n * CAP_ + j];
        float pv = pval[d];
        ushort4 hv = *(const ushort4*)(h + (size_t)d * 64 + c4);
        p.x = fmaf(pv, bfup(hv.x), p.x);
        p.y = fmaf(pv, bfup(hv.y), p.y);
        p.z = fmaf(pv, bfup(hv.z), p.z);
        p.w = fmaf(pv, bfup(hv.w), p.w);
    }
    int novf = *ovfc;
    if (novf > 0) {
        int ne = novf < OVF_MAX ? novf : OVF_MAX;
        for (int e = 0; e < ne; ++e) {
            int d = ovf[e];
            if (prow[d] == n) {
                float pv = pval[d];
                ushort4 hv = *(const ushort4*)(h + (size_t)d * 64 + c4);
                p.x = fmaf(pv, bfup(hv.x), p.x);
                p.y = fmaf(pv, bfup(hv.y), p.y);
                p.z = fmaf(pv, bfup(hv.z), p.z);
                p.w = fmaf(pv, bfup(hv.w), p.w);
            }
        }
    }
    const float4* tf = (const float4*)(tab + (size_t)(seg * 64 + c4) * 2);
    float4 t0 = tf[0], t1 = tf[1];
    float4 xo;
    xo.x = p.x * fmaf(t0.x, dgv, t0.y);
    xo.y = p.y * fmaf(t0.z, dgv, t0.w);
    xo.z = p.z * fmaf(t1.x, dgv, t1.y);
    xo.w = p.w * fmaf(t1.z, dgv, t1.w);
    if (last) {
        *(float4*)(x + (size_t)n * 64 + c4) = xo;
    } else {
        ushort4 s;
        s.x = f32_to_bf16(xo.x); s.y = f32_to_bf16(xo.y);
        s.z = f32_to_bf16(xo.z); s.w = f32_to_bf16(xo.w);
        *(ushort4*)(xbo + (size_t)n * 64 + c4) = s;
    }
}

// ---------------------------------------------------------------------------
__global__ __launch_bounds__(256) void k_gpool(const float* __restrict__ x,
                                               const int* __restrict__ batch,
                                               float* __restrict__ out,
                                               float* __restrict__ cnt) {
    int wave = (blockIdx.x * 256 + threadIdx.x) >> 6;
    int lane = threadIdx.x & 63;
    int n0 = wave * 64;
    if (n0 >= N_NODES) return;
    int n1 = min(n0 + 64, N_NODES);
    int g = batch[n0];
    float s = 0.f, c = 0.f;
    for (int n = n0; n < n1; ++n) {
        int gn = batch[n];
        if (gn != g) {
            atomicAdd(out + (size_t)g * 64 + lane, s);
            if (lane == 0) atomicAdd(cnt + g, c);
            s = 0.f; c = 0.f; g = gn;
        }
        s += x[(size_t)n * 64 + lane];
        c += 1.f;
    }
    atomicAdd(out + (size_t)g * 64 + lane, s);
    if (lane == 0) atomicAdd(cnt + g, c);
}

__global__ __launch_bounds__(256) void k_gdiv(float* __restrict__ out,
                                              const float* __restrict__ cnt) {
    int idx = blockIdx.x * 256 + threadIdx.x;
    if (idx >= G_ * 64) return;
    out[idx] /= fmaxf(cnt[idx >> 6], 1.f);
}

// ---------------------------------------------------------------------------
extern "C" void kernel_launch(void* const* d_in, const int* in_sizes, int n_in,
                              void* d_out, int out_size, void* d_ws, size_t ws_size,
                              hipStream_t stream) {
    const float* node_feat = (const float*)d_in[0];
    const float* degs      = (const float*)d_in[1];
    const int*   batch     = (const int*)  d_in[2];
    const int*   n2p_col   = (const int*)  d_in[4];
    const float* n2p_val   = (const float*)d_in[5];
    const float* e2p_val   = (const float*)d_in[8];
    const int*   pool_row  = (const int*)  d_in[9];
    const float* pool_val  = (const float*)d_in[11];
    const float* atom_W    = (const float*)d_in[12];
    const float* atom_b    = (const float*)d_in[13];
    const float* edge_W    = (const float*)d_in[14];
    const float* edge_b    = (const float*)d_in[15];
    const float* W_lrp     = (const float*)d_in[16];
    const float* b_lrp     = (const float*)d_in[17];
    const float* dn0_W     = (const float*)d_in[18];
    const float* dn0_b     = (const float*)d_in[19];
    const float* dn1_W     = (const float*)d_in[20];
    const float* dn1_b     = (const float*)d_in[21];

    char* ws = (char*)d_ws;
    unsigned short* h      = (unsigned short*)(ws);                 // 12,800,000
    unsigned short* xb     = (unsigned short*)(ws + 12800000);      // 12,800,000
    unsigned short* Wth    = (unsigned short*)(ws + 25600000);      //    524,288
    unsigned short* Wtl    = (unsigned short*)(ws + 26124288);      //    524,288
    int*            bucket = (int*)           (ws + 26648576);      //  8,000,000
    int*            cntn   = (int*)           (ws + 34648576);      //    400,000
    int*            ovf    = (int*)           (ws + 35048576);      //     16,384
    int*            ovfc   = (int*)           (ws + 35064960);      //        128
    float*          tab    = (float*)         (ws + 35065088);      //    264,192
    float*          thr    = (float*)         (ws + 35329280);      //      2,048
    float*          cntg   = (float*)         (ws + 35331328);      //      4,096
    float*          x      = (float*)         (ws + 35335424);      // 25,600,000

    hipLaunchKernelGGL(k_prep_w, dim3(1024), dim3(256), 0, stream, W_lrp, Wth, Wtl);
    hipLaunchKernelGGL(k_prep_factor, dim3(4, 8), dim3(256), 0, stream,
                       dn0_W, dn0_b, dn1_W, dn1_b, tab, thr);
    hipLaunchKernelGGL(k_atom, dim3(25000), dim3(256), 0, stream,
                       node_feat, atom_W, atom_b, xb);
    hipMemsetAsync(cntn, 0, 416512, stream);   // cntn + ovf + ovfc in one shot
    hipLaunchKernelGGL(k_bucket, dim3(391), dim3(256), 0, stream,
                       pool_row, cntn, bucket, ovf, ovfc);
    for (int i = 0; i < 4; ++i) {
        hipLaunchKernelGGL(k_lrp, dim3(1563), dim3(256), 0, stream,
                           xb, n2p_col, n2p_val, e2p_val, edge_W, edge_b,
                           Wth + (size_t)i * 65536, Wtl + (size_t)i * 65536,
                           b_lrp + i * 64, h);
        hipLaunchKernelGGL(k_pool_seg, dim3(6250), dim3(256), 0, stream,
                           h, cntn, bucket, ovf, ovfc, pool_row, pool_val,
                           degs, tab + (size_t)i * 129 * 128, thr + i * 128,
                           x, xb, (i == 3) ? 1 : 0);
    }
    hipMemsetAsync(d_out, 0, (size_t)G_ * 64 * 4, stream);
    hipMemsetAsync(cntg, 0, G_ * 4, stream);
    hipLaunchKernelGGL(k_gpool, dim3(391), dim3(256), 0, stream,
                       x, batch, (float*)d_out, cntg);
    hipLaunchKernelGGL(k_gdiv, dim3(256), dim3(256), 0, stream,
                       (float*)d_out, cntg);
}